// Round 1
// baseline (620.614 us; speedup 1.0000x reference)
//
#include <hip/hip_runtime.h>
#include <stdint.h>

// ---------------------------------------------------------------------------
// MultiHeadAttention: out = LN(FC(Attn(QWq, KWk, VWv, mask))), plus attn probs.
// B=32 H=8 L=512 Dmodel=512 Dh=64. All f32 in/out; bf16 MFMA internally.
// Workspace layout (bytes), total 154,140,672 (~147 MB):
//   qb,kb,vb   bf16 copies of q,k,v            3 x 16,777,216
//   wqb,wkb,wvb,fcwb bf16 weights              4 x    524,288
//   qh,kh      bf16 [b][h][l][d]               2 x 16,777,216
//   vt         bf16 [b][h][d][l] (transposed)      16,777,216
//   oh         bf16 [b][l][h*64+d]                 16,777,216
//   fco        f32  [16384][512]                   33,554,432
//   pmask      u64 bit-packed mask                  1,048,576
// ---------------------------------------------------------------------------

typedef float f32x4 __attribute__((ext_vector_type(4)));
typedef __bf16 bf16x8 __attribute__((ext_vector_type(8)));

#define DEV __device__ __forceinline__

DEV uint16_t f2bf(float f) {
  uint32_t u = __builtin_bit_cast(uint32_t, f);
  u += 0x7fffu + ((u >> 16) & 1u);   // RNE
  return (uint16_t)(u >> 16);
}

DEV void gload_lds16(const void* g, void* l) {
  __builtin_amdgcn_global_load_lds((const __attribute__((address_space(1))) uint32_t*)g,
                                   (__attribute__((address_space(3))) uint32_t*)l, 16, 0, 0);
}

// ---------------- f32 -> bf16 bulk convert ----------------
__global__ __launch_bounds__(256) void cvt_bf16(const float* __restrict__ src,
                                                uint16_t* __restrict__ dst, int n4) {
  int i = blockIdx.x * 256 + threadIdx.x;
  if (i >= n4) return;
  f32x4 v = ((const f32x4*)src)[i];
  ushort4 o;
  o.x = f2bf(v.x); o.y = f2bf(v.y); o.z = f2bf(v.z); o.w = f2bf(v.w);
  ((ushort4*)dst)[i] = o;
}

// ---------------- mask (int32 0/1) -> bit-packed u64 ----------------
__global__ __launch_bounds__(256) void pack_mask(const int* __restrict__ m,
                                                 unsigned long long* __restrict__ pm, int nw) {
  int t = blockIdx.x * 256 + threadIdx.x;
  int wid = t >> 6, lane = t & 63;
  if (wid >= nw) return;
  int v = m[(size_t)wid * 64 + lane];
  unsigned long long bits = __ballot(v != 0);
  if (lane == 0) pm[wid] = bits;
}

// ---------------- NT GEMM: C[16384x512] = A[16384x512] * W[512x512]^T ------
// 128x128 tile, BK=64, 256 thr (4 waves 2x2), double-buffered LDS,
// global_load_lds w/ pre-swizzled source (XOR swizzle ((row&7)<<4) on bytes).
// EPI 0: bf16 scatter to qh/kh [b][h][l][d]
// EPI 1: bf16 scatter to vt    [b][h][d][l]  (4 consecutive l -> ushort4)
// EPI 2: f32 to fco [m][n]
template <int EPI>
__global__ __launch_bounds__(256) void gemm_nt(const uint16_t* __restrict__ A,
                                               const uint16_t* __restrict__ Bw,
                                               void* __restrict__ outp) {
  __shared__ uint16_t As[2][128 * 64];
  __shared__ uint16_t Bs[2][128 * 64];
  const int t = threadIdx.x;
  const int lane = t & 63;
  const int w = t >> 6;
  const int bn = blockIdx.x & 3;
  const int bm = blockIdx.x >> 2;
  const char* Ab = (const char*)(A + (size_t)bm * 128 * 512);
  const char* Bb = (const char*)(Bw + (size_t)bn * 128 * 512);
  const int l15 = lane & 15, l4 = lane >> 4;
  const int wr = (w >> 1) * 64, wc = (w & 1) * 64;

  auto stage = [&](int buf, int kt) {
    const int kb = kt * 128;  // byte offset of k0 within a 1024B global row
#pragma unroll
    for (int i = 0; i < 4; ++i) {
      int o = i * 4096 + t * 16;
      int row = o >> 7, cb = o & 127;
      int sw = cb ^ ((row & 7) << 4);
      gload_lds16(Ab + (size_t)row * 1024 + kb + sw, (char*)As[buf] + i * 4096 + (t & 192) * 16);
      gload_lds16(Bb + (size_t)row * 1024 + kb + sw, (char*)Bs[buf] + i * 4096 + (t & 192) * 16);
    }
  };

  f32x4 acc[4][4] = {};
  stage(0, 0);
  __syncthreads();
#pragma unroll 1
  for (int kt = 0; kt < 8; ++kt) {
    int cur = kt & 1;
    if (kt < 7) stage(cur ^ 1, kt + 1);  // overlap next-tile loads with compute
#pragma unroll
    for (int kk = 0; kk < 2; ++kk) {
      bf16x8 af[4], bf[4];
#pragma unroll
      for (int i = 0; i < 4; ++i) {
        int ar = wr + i * 16 + l15;
        af[i] = *(const bf16x8*)((const char*)As[cur] + ar * 128 +
                                 ((kk * 64 + l4 * 16) ^ ((ar & 7) << 4)));
        int br = wc + i * 16 + l15;
        bf[i] = *(const bf16x8*)((const char*)Bs[cur] + br * 128 +
                                 ((kk * 64 + l4 * 16) ^ ((br & 7) << 4)));
      }
#pragma unroll
      for (int i = 0; i < 4; ++i)
#pragma unroll
        for (int j = 0; j < 4; ++j)
          acc[i][j] = __builtin_amdgcn_mfma_f32_16x16x32_bf16(af[i], bf[j], acc[i][j], 0, 0, 0);
    }
    __syncthreads();
  }

  const int m0 = bm * 128 + wr + l4 * 4;
  const int n0 = bn * 128 + wc + l15;
#pragma unroll
  for (int i = 0; i < 4; ++i) {
#pragma unroll
    for (int j = 0; j < 4; ++j) {
      int mm = m0 + i * 16;
      int nn = n0 + j * 16;
      if (EPI == 2) {
        float* dst = (float*)outp + (size_t)mm * 512 + nn;
#pragma unroll
        for (int r = 0; r < 4; ++r) dst[(size_t)r * 512] = acc[i][j][r];
      } else {
        int b = mm >> 9, l = mm & 511;
        int h = nn >> 6, d = nn & 63;
        if (EPI == 0) {
          uint16_t* dst = (uint16_t*)outp + ((size_t)(b * 8 + h) * 512 + l) * 64 + d;
#pragma unroll
          for (int r = 0; r < 4; ++r) dst[(size_t)r * 64] = f2bf(acc[i][j][r]);
        } else {
          uint16_t* dst = (uint16_t*)outp + ((size_t)(b * 8 + h) * 64 + d) * 512 + l;
          ushort4 o;
          o.x = f2bf(acc[i][j][0]); o.y = f2bf(acc[i][j][1]);
          o.z = f2bf(acc[i][j][2]); o.w = f2bf(acc[i][j][3]);
          *(ushort4*)dst = o;
        }
      }
    }
  }
}

// ---------------- fused attention ----------------
// grid 2048 = B*H*8 ; block 512 thr (8 waves); 64 Q rows per block.
// Wave w owns S cols {w*32..w*32+31} and {256+w*32..+31} (4 col-frags).
// PV: wave w -> d-frag (w&3), q-frags {2*(w>>2), 2*(w>>2)+1}.
__global__ __launch_bounds__(512) void attn_fused(const uint16_t* __restrict__ qh,
                                                  const uint16_t* __restrict__ kh,
                                                  const uint16_t* __restrict__ vtp,
                                                  const unsigned long long* __restrict__ pm,
                                                  float* __restrict__ attn_out,
                                                  uint16_t* __restrict__ oh) {
  __shared__ uint16_t Qs[64 * 64];    //  8KB rows=q   RB=128B
  __shared__ uint16_t Ks[256 * 64];   // 32KB rows=kcol RB=128B (2 phases)
  __shared__ uint16_t VTs[64 * 256];  // 32KB rows=d   RB=512B (2 phases)
  __shared__ uint16_t Ps[64 * 512];   // 64KB rows=q   RB=1024B
  __shared__ float red8[64 * 8];
  __shared__ float redF[64];
  __shared__ float redS[64];

  const int bid = blockIdx.x;
  const int qb = bid & 7, h = (bid >> 3) & 7, b = bid >> 6;
  const int t = threadIdx.x, lane = t & 63, w = t >> 6;
  const int l15 = lane & 15, l4 = lane >> 4;
  const int q0 = qb * 64;
  const char* qbase = (const char*)(qh + ((size_t)(b * 8 + h) * 512 + q0) * 64);
  const char* kbase = (const char*)(kh + (size_t)(b * 8 + h) * 512 * 64);
  const char* vbase = (const char*)(vtp + (size_t)(b * 8 + h) * 64 * 512);

  auto stageK = [&](int p) {
#pragma unroll
    for (int i = 0; i < 4; ++i) {
      int o = i * 8192 + t * 16, row = o >> 7, cb = o & 127;
      gload_lds16(kbase + (size_t)(p * 256 + row) * 128 + (cb ^ ((row & 7) << 4)),
                  (char*)Ks + i * 8192 + (t & 448) * 16);
    }
  };
  auto stageV = [&](int p) {
#pragma unroll
    for (int i = 0; i < 4; ++i) {
      int o = i * 8192 + t * 16, row = o >> 9, cb = o & 511;
      gload_lds16(vbase + (size_t)row * 1024 + p * 512 + (cb ^ ((row & 7) << 4)),
                  (char*)VTs + i * 8192 + (t & 448) * 16);
    }
  };
  {  // stage Q (8KB: one 16B load per thread)
    int o = t * 16, row = o >> 7, cb = o & 127;
    gload_lds16(qbase + (size_t)row * 128 + (cb ^ ((row & 7) << 4)), (char*)Qs + (t & 448) * 16);
  }
  stageK(0);
  stageV(0);
  __syncthreads();

  bf16x8 af[4][2];
#pragma unroll
  for (int fq = 0; fq < 4; ++fq)
#pragma unroll
    for (int kk = 0; kk < 2; ++kk) {
      int ar = fq * 16 + l15;
      af[fq][kk] = *(const bf16x8*)((const char*)Qs + ar * 128 +
                                    ((kk * 64 + l4 * 16) ^ ((ar & 7) << 4)));
    }

  f32x4 sacc[4][4] = {};  // [q-frag][col-frag]; col-frags 0,1 = phase0, 2,3 = phase1
#pragma unroll
  for (int fc = 0; fc < 2; ++fc) {
    int brow = w * 32 + fc * 16 + l15;
    bf16x8 b0 = *(const bf16x8*)((const char*)Ks + brow * 128 + ((l4 * 16) ^ ((brow & 7) << 4)));
    bf16x8 b1 = *(const bf16x8*)((const char*)Ks + brow * 128 + ((64 + l4 * 16) ^ ((brow & 7) << 4)));
#pragma unroll
    for (int fq = 0; fq < 4; ++fq) {
      sacc[fq][fc] = __builtin_amdgcn_mfma_f32_16x16x32_bf16(af[fq][0], b0, sacc[fq][fc], 0, 0, 0);
      sacc[fq][fc] = __builtin_amdgcn_mfma_f32_16x16x32_bf16(af[fq][1], b1, sacc[fq][fc], 0, 0, 0);
    }
  }
  __syncthreads();
  stageK(1);
  __syncthreads();
#pragma unroll
  for (int fc = 0; fc < 2; ++fc) {
    int brow = w * 32 + fc * 16 + l15;  // local row = global col - 256
    bf16x8 b0 = *(const bf16x8*)((const char*)Ks + brow * 128 + ((l4 * 16) ^ ((brow & 7) << 4)));
    bf16x8 b1 = *(const bf16x8*)((const char*)Ks + brow * 128 + ((64 + l4 * 16) ^ ((brow & 7) << 4)));
#pragma unroll
    for (int fq = 0; fq < 4; ++fq) {
      sacc[fq][2 + fc] = __builtin_amdgcn_mfma_f32_16x16x32_bf16(af[fq][0], b0, sacc[fq][2 + fc], 0, 0, 0);
      sacc[fq][2 + fc] = __builtin_amdgcn_mfma_f32_16x16x32_bf16(af[fq][1], b1, sacc[fq][2 + fc], 0, 0, 0);
    }
  }

  // ---- softmax: scale, mask (bit-packed), wave-parallel row reductions ----
  const size_t pmbase = ((size_t)b * 512 + q0) * 8;
#pragma unroll
  for (int fq = 0; fq < 4; ++fq) {
#pragma unroll
    for (int i = 0; i < 4; ++i) {
      int r = fq * 16 + l4 * 4 + i;
      unsigned long long m0 = pm[pmbase + r * 8 + (w >> 1)];
      unsigned long long m1 = pm[pmbase + r * 8 + 4 + (w >> 1)];
      int bit0 = (w & 1) * 32 + l15;
      float vmax = -3.0e38f;
#pragma unroll
      for (int fc = 0; fc < 4; ++fc) {
        unsigned long long word = (fc < 2) ? m0 : m1;
        int bit = bit0 + (fc & 1) * 16;
        bool mk = (word >> bit) & 1ull;
        float sv = sacc[fq][fc][i] * 0.125f;  // /sqrt(64)
        sv = mk ? -1.0e30f : sv;              // masked_fill
        sacc[fq][fc][i] = sv;
        vmax = fmaxf(vmax, sv);
      }
      vmax = fmaxf(vmax, __shfl_xor(vmax, 1));
      vmax = fmaxf(vmax, __shfl_xor(vmax, 2));
      vmax = fmaxf(vmax, __shfl_xor(vmax, 4));
      vmax = fmaxf(vmax, __shfl_xor(vmax, 8));
      if (l15 == 0) red8[r * 8 + w] = vmax;
    }
  }
  __syncthreads();
  if (t < 64) {
    float m = red8[t * 8];
#pragma unroll
    for (int j = 1; j < 8; ++j) m = fmaxf(m, red8[t * 8 + j]);
    redF[t] = m;
  }
  __syncthreads();
#pragma unroll
  for (int fq = 0; fq < 4; ++fq) {
#pragma unroll
    for (int i = 0; i < 4; ++i) {
      int r = fq * 16 + l4 * 4 + i;
      float mx = redF[r];
      float s = 0.f;
#pragma unroll
      for (int fc = 0; fc < 4; ++fc) {
        float sv = sacc[fq][fc][i];
        float p = (sv < -1.0e29f) ? 0.f : __expf(sv - mx);
        sacc[fq][fc][i] = p;
        s += p;
      }
      s += __shfl_xor(s, 1); s += __shfl_xor(s, 2);
      s += __shfl_xor(s, 4); s += __shfl_xor(s, 8);
      if (l15 == 0) red8[r * 8 + w] = s;
    }
  }
  __syncthreads();
  if (t < 64) {
    float s = 0.f;
#pragma unroll
    for (int j = 0; j < 8; ++j) s += red8[t * 8 + j];
    redS[t] = 1.0f / s;
  }
  __syncthreads();

  float* abase = attn_out + ((size_t)(h * 32 + b) * 512 + q0) * 512;
#pragma unroll
  for (int fq = 0; fq < 4; ++fq) {
#pragma unroll
    for (int i = 0; i < 4; ++i) {
      int r = fq * 16 + l4 * 4 + i;
      float rinv = redS[r];
#pragma unroll
      for (int fc = 0; fc < 4; ++fc) {
        int c = ((fc >= 2) ? 256 : 0) + w * 32 + (fc & 1) * 16 + l15;
        float p = sacc[fq][fc][i] * rinv;
        abase[(size_t)r * 512 + c] = p;  // attn output, f32
        *(uint16_t*)((char*)Ps + r * 1024 + ((c * 2) ^ ((r & 7) << 4))) = f2bf(p);
      }
    }
  }
  __syncthreads();

  // ---- PV: O[64x64] = P[64x512] * V[512x64] via VT rows ----
  const int dfrag = w & 3, qsel = w >> 2;
  f32x4 oacc[2] = {};
  auto pvphase = [&](int p) {
#pragma unroll
    for (int ks = 0; ks < 8; ++ks) {
      int brow = dfrag * 16 + l15;  // VT row = d
      bf16x8 bf = *(const bf16x8*)((const char*)VTs + brow * 512 +
                                   ((ks * 64 + l4 * 16) ^ ((brow & 7) << 4)));
#pragma unroll
      for (int qi = 0; qi < 2; ++qi) {
        int arow = (qsel * 2 + qi) * 16 + l15;
        int kb = (p * 256 + ks * 32 + l4 * 8) * 2;
        bf16x8 ap = *(const bf16x8*)((const char*)Ps + arow * 1024 + (kb ^ ((arow & 7) << 4)));
        oacc[qi] = __builtin_amdgcn_mfma_f32_16x16x32_bf16(ap, bf, oacc[qi], 0, 0, 0);
      }
    }
  };
  pvphase(0);
  __syncthreads();
  stageV(1);
  __syncthreads();
  pvphase(1);

#pragma unroll
  for (int qi = 0; qi < 2; ++qi) {
    int qrow = (qsel * 2 + qi) * 16 + l4 * 4;
    int d = dfrag * 16 + l15;
    uint16_t* dst = oh + ((size_t)(b * 512 + q0 + qrow)) * 512 + h * 64 + d;
#pragma unroll
    for (int r = 0; r < 4; ++r) dst[(size_t)r * 512] = f2bf(oacc[qi][r]);
  }
}

// ---------------- LayerNorm (+FC bias) ----------------
__global__ __launch_bounds__(256) void ln_kernel(const float* __restrict__ x,
                                                 const float* __restrict__ bias,
                                                 const float* __restrict__ g,
                                                 const float* __restrict__ bt,
                                                 float* __restrict__ out) {
  int w = threadIdx.x >> 6, lane = threadIdx.x & 63;
  int row = blockIdx.x * 4 + w;
  const float* xr = x + (size_t)row * 512;
  float v[8];
  float s = 0.f;
#pragma unroll
  for (int j = 0; j < 8; ++j) {
    v[j] = xr[lane + j * 64] + bias[lane + j * 64];
    s += v[j];
  }
#pragma unroll
  for (int m = 32; m >= 1; m >>= 1) s += __shfl_xor(s, m);
  float mu = s * (1.f / 512.f);
  float var = 0.f;
#pragma unroll
  for (int j = 0; j < 8; ++j) { float d = v[j] - mu; var += d * d; }
#pragma unroll
  for (int m = 32; m >= 1; m >>= 1) var += __shfl_xor(var, m);
  float rstd = rsqrtf(var * (1.f / 512.f) + 1e-5f);
  float* orow = out + (size_t)row * 512;
#pragma unroll
  for (int j = 0; j < 8; ++j)
    orow[lane + j * 64] = (v[j] - mu) * rstd * g[lane + j * 64] + bt[lane + j * 64];
}

// ---------------------------------------------------------------------------
extern "C" void kernel_launch(void* const* d_in, const int* in_sizes, int n_in,
                              void* d_out, int out_size, void* d_ws, size_t ws_size,
                              hipStream_t stream) {
  (void)in_sizes; (void)n_in; (void)out_size; (void)ws_size;
  const float* q   = (const float*)d_in[0];
  const float* k   = (const float*)d_in[1];
  const float* v   = (const float*)d_in[2];
  const int*   msk = (const int*)d_in[3];   // bool mask, assumed int32 per harness
  const float* Wq  = (const float*)d_in[4];
  const float* Wk  = (const float*)d_in[5];
  const float* Wv  = (const float*)d_in[6];
  const float* fcw = (const float*)d_in[7];
  const float* fcb = (const float*)d_in[8];
  const float* lng = (const float*)d_in[9];
  const float* lnb = (const float*)d_in[10];
  float* outp = (float*)d_out;

  char* ws = (char*)d_ws;
  uint16_t* qb_  = (uint16_t*)(ws);
  uint16_t* kb_  = (uint16_t*)(ws + 16777216);
  uint16_t* vb_  = (uint16_t*)(ws + 2 * 16777216);
  uint16_t* wqb  = (uint16_t*)(ws + 3 * 16777216);
  uint16_t* wkb  = (uint16_t*)(ws + 3 * 16777216 + 524288);
  uint16_t* wvb  = (uint16_t*)(ws + 3 * 16777216 + 2 * 524288);
  uint16_t* fcwb = (uint16_t*)(ws + 3 * 16777216 + 3 * 524288);
  uint16_t* qh   = (uint16_t*)(ws + 3 * 16777216 + 4 * 524288);
  uint16_t* kh   = qh + 8388608;
  uint16_t* vt   = kh + 8388608;
  uint16_t* oh   = vt + 8388608;
  float*    fco  = (float*)(oh + 8388608);
  unsigned long long* pmask = (unsigned long long*)((char*)fco + 33554432);

  cvt_bf16<<<8192, 256, 0, stream>>>(q, qb_, 2097152);
  cvt_bf16<<<8192, 256, 0, stream>>>(k, kb_, 2097152);
  cvt_bf16<<<8192, 256, 0, stream>>>(v, vb_, 2097152);
  cvt_bf16<<<256, 256, 0, stream>>>(Wq, wqb, 65536);
  cvt_bf16<<<256, 256, 0, stream>>>(Wk, wkb, 65536);
  cvt_bf16<<<256, 256, 0, stream>>>(Wv, wvb, 65536);
  cvt_bf16<<<256, 256, 0, stream>>>(fcw, fcwb, 65536);
  pack_mask<<<32768, 256, 0, stream>>>(msk, pmask, 131072);

  gemm_nt<0><<<512, 256, 0, stream>>>(qb_, wqb, qh);
  gemm_nt<0><<<512, 256, 0, stream>>>(kb_, wkb, kh);
  gemm_nt<1><<<512, 256, 0, stream>>>(vb_, wvb, vt);

  attn_fused<<<2048, 512, 0, stream>>>(qh, kh, vt, pmask, outp + 8388608, oh);

  gemm_nt<2><<<512, 256, 0, stream>>>(oh, fcwb, fco);
  ln_kernel<<<4096, 256, 0, stream>>>(fco, fcb, lng, lnb, outp);
}

// Round 2
// 601.335 us; speedup vs baseline: 1.0321x; 1.0321x over previous
//
#include <hip/hip_runtime.h>
#include <stdint.h>

// ---------------------------------------------------------------------------
// MultiHeadAttention: out = LN(FC(Attn(QWq, KWk, VWv, mask))), plus attn probs.
// B=32 H=8 L=512 Dmodel=512 Dh=64. f32 in/out; bf16 MFMA internally.
// R2: attn restructured — no K/V LDS staging (direct global->reg B-frags),
//     3 barriers, 68.5KB LDS -> 2 blocks/CU, full-line coalesced attn writes,
//     XCD-chunked block swizzles, launch count 13 -> 7.
// ---------------------------------------------------------------------------

typedef float f32x4 __attribute__((ext_vector_type(4)));
typedef __bf16 bf16x8 __attribute__((ext_vector_type(8)));
typedef unsigned short ushort8 __attribute__((ext_vector_type(8)));

#define DEV __device__ __forceinline__

DEV uint16_t f2bf(float f) {
  uint32_t u = __builtin_bit_cast(uint32_t, f);
  u += 0x7fffu + ((u >> 16) & 1u);   // RNE
  return (uint16_t)(u >> 16);
}

DEV void gload_lds16(const void* g, void* l) {
  __builtin_amdgcn_global_load_lds((const __attribute__((address_space(1))) uint32_t*)g,
                                   (__attribute__((address_space(3))) uint32_t*)l, 16, 0, 0);
}

// ---------------- f32 -> bf16 bulk converts (q,k,v merged; weights merged) --
__global__ __launch_bounds__(256) void cvt_qkv(const float* __restrict__ q,
                                               const float* __restrict__ k,
                                               const float* __restrict__ v,
                                               uint16_t* __restrict__ qo,
                                               uint16_t* __restrict__ ko,
                                               uint16_t* __restrict__ vo) {
  int g = blockIdx.x >> 13;
  int i = (blockIdx.x & 8191) * 256 + threadIdx.x;
  const float* s = g == 0 ? q : g == 1 ? k : v;
  uint16_t* d = g == 0 ? qo : g == 1 ? ko : vo;
  f32x4 val = ((const f32x4*)s)[i];
  ushort4 o;
  o.x = f2bf(val.x); o.y = f2bf(val.y); o.z = f2bf(val.z); o.w = f2bf(val.w);
  ((ushort4*)d)[i] = o;
}

__global__ __launch_bounds__(256) void cvt_w(const float* __restrict__ w0,
                                             const float* __restrict__ w1,
                                             const float* __restrict__ w2,
                                             const float* __restrict__ w3,
                                             uint16_t* __restrict__ d0,
                                             uint16_t* __restrict__ d1,
                                             uint16_t* __restrict__ d2,
                                             uint16_t* __restrict__ d3) {
  int g = blockIdx.x >> 8;
  int i = (blockIdx.x & 255) * 256 + threadIdx.x;
  const float* s = g == 0 ? w0 : g == 1 ? w1 : g == 2 ? w2 : w3;
  uint16_t* d = g == 0 ? d0 : g == 1 ? d1 : g == 2 ? d2 : d3;
  f32x4 val = ((const f32x4*)s)[i];
  ushort4 o;
  o.x = f2bf(val.x); o.y = f2bf(val.y); o.z = f2bf(val.z); o.w = f2bf(val.w);
  ((ushort4*)d)[i] = o;
}

// ---------------- mask (int32 0/1) -> bit-packed u64 ----------------
__global__ __launch_bounds__(256) void pack_mask(const int* __restrict__ m,
                                                 unsigned long long* __restrict__ pm, int nw) {
  int t = blockIdx.x * 256 + threadIdx.x;
  int wid = t >> 6, lane = t & 63;
  if (wid >= nw) return;
  int v = m[(size_t)wid * 64 + lane];
  unsigned long long bits = __ballot(v != 0);
  if (lane == 0) pm[wid] = bits;
}

// ---------------- GEMM core macro: 128x128 tile, BK=64, dbuf LDS -----------
// As/Bs must be __shared__ uint16_t [2][128*64]. Produces acc[4][4] f32x4.
#define GEMM_CORE(Ab, Bb, As, Bs, acc)                                          \
  {                                                                             \
    auto stage = [&](int buf, int kt) {                                         \
      const int kb = kt * 128;                                                  \
      _Pragma("unroll") for (int i_ = 0; i_ < 4; ++i_) {                        \
        int o_ = i_ * 4096 + t * 16;                                            \
        int row_ = o_ >> 7, cb_ = o_ & 127;                                     \
        int sw_ = cb_ ^ ((row_ & 7) << 4);                                      \
        gload_lds16(Ab + (size_t)row_ * 1024 + kb + sw_,                        \
                    (char*)As[buf] + i_ * 4096 + (t & 192) * 16);               \
        gload_lds16(Bb + (size_t)row_ * 1024 + kb + sw_,                        \
                    (char*)Bs[buf] + i_ * 4096 + (t & 192) * 16);               \
      }                                                                         \
    };                                                                          \
    stage(0, 0);                                                                \
    __syncthreads();                                                            \
    _Pragma("unroll 1") for (int kt = 0; kt < 8; ++kt) {                        \
      int cur = kt & 1;                                                         \
      if (kt < 7) stage(cur ^ 1, kt + 1);                                       \
      _Pragma("unroll") for (int kk = 0; kk < 2; ++kk) {                        \
        bf16x8 af_[4], bf_[4];                                                  \
        _Pragma("unroll") for (int i_ = 0; i_ < 4; ++i_) {                      \
          int ar_ = wr + i_ * 16 + l15;                                         \
          af_[i_] = *(const bf16x8*)((const char*)As[cur] + ar_ * 128 +         \
                                     ((kk * 64 + l4 * 16) ^ ((ar_ & 7) << 4))); \
          int br_ = wc + i_ * 16 + l15;                                         \
          bf_[i_] = *(const bf16x8*)((const char*)Bs[cur] + br_ * 128 +         \
                                     ((kk * 64 + l4 * 16) ^ ((br_ & 7) << 4))); \
        }                                                                       \
        _Pragma("unroll") for (int i_ = 0; i_ < 4; ++i_)                        \
            _Pragma("unroll") for (int j_ = 0; j_ < 4; ++j_)                    \
                acc[i_][j_] = __builtin_amdgcn_mfma_f32_16x16x32_bf16(          \
                    af_[i_], bf_[j_], acc[i_][j_], 0, 0, 0);                    \
      }                                                                         \
      __syncthreads();                                                          \
    }                                                                           \
  }

// XCD-chunked remap within a 512-block group: all 4 bn of a bm-chunk on 1 XCD.
#define GEMM_BLOCKMAP()                        \
  const int local = blockIdx.x & 511;          \
  const int bm = (local & 7) * 16 + ((local >> 3) >> 2); \
  const int bn = (local >> 3) & 3;             \
  const int t = threadIdx.x;                   \
  const int lane = t & 63;                     \
  const int w = t >> 6;                        \
  const int l15 = lane & 15, l4 = lane >> 4;   \
  const int wr = (w >> 1) * 64, wc = (w & 1) * 64;

// ---------------- merged projection GEMMs (q,k,v) ----------------
__global__ __launch_bounds__(256) void gemm_proj(const uint16_t* __restrict__ qb,
                                                 const uint16_t* __restrict__ kb,
                                                 const uint16_t* __restrict__ vb,
                                                 const uint16_t* __restrict__ wq,
                                                 const uint16_t* __restrict__ wk,
                                                 const uint16_t* __restrict__ wv,
                                                 uint16_t* __restrict__ qh,
                                                 uint16_t* __restrict__ kh,
                                                 uint16_t* __restrict__ vt) {
  __shared__ uint16_t As[2][128 * 64];
  __shared__ uint16_t Bs[2][128 * 64];
  const int g = blockIdx.x >> 9;
  GEMM_BLOCKMAP();
  const uint16_t* A = g == 0 ? qb : g == 1 ? kb : vb;
  const uint16_t* W = g == 0 ? wq : g == 1 ? wk : wv;
  const char* Ab = (const char*)(A + (size_t)bm * 128 * 512);
  const char* Bb = (const char*)(W + (size_t)bn * 128 * 512);
  f32x4 acc[4][4] = {};
  GEMM_CORE(Ab, Bb, As, Bs, acc);

  const int m0 = bm * 128 + wr + l4 * 4;
  const int n0 = bn * 128 + wc + l15;
#pragma unroll
  for (int i = 0; i < 4; ++i) {
#pragma unroll
    for (int j = 0; j < 4; ++j) {
      int mm = m0 + i * 16, nn = n0 + j * 16;
      int b = mm >> 9, l = mm & 511;
      int h = nn >> 6, d = nn & 63;
      if (g < 2) {  // [b][h][l][d]
        uint16_t* dst = (g == 0 ? qh : kh) + ((size_t)(b * 8 + h) * 512 + l) * 64 + d;
#pragma unroll
        for (int r = 0; r < 4; ++r) dst[(size_t)r * 64] = f2bf(acc[i][j][r]);
      } else {      // vt [b][h][d][l]
        uint16_t* dst = vt + ((size_t)(b * 8 + h) * 64 + d) * 512 + l;
        ushort4 o;
        o.x = f2bf(acc[i][j][0]); o.y = f2bf(acc[i][j][1]);
        o.z = f2bf(acc[i][j][2]); o.w = f2bf(acc[i][j][3]);
        *(ushort4*)dst = o;
      }
    }
  }
}

// ---------------- FC GEMM: fco[16384x512] f32 = oh x fcw^T ----------------
__global__ __launch_bounds__(256) void gemm_fc(const uint16_t* __restrict__ A,
                                               const uint16_t* __restrict__ W,
                                               float* __restrict__ fco) {
  __shared__ uint16_t As[2][128 * 64];
  __shared__ uint16_t Bs[2][128 * 64];
  GEMM_BLOCKMAP();
  const char* Ab = (const char*)(A + (size_t)bm * 128 * 512);
  const char* Bb = (const char*)(W + (size_t)bn * 128 * 512);
  f32x4 acc[4][4] = {};
  GEMM_CORE(Ab, Bb, As, Bs, acc);

  const int m0 = bm * 128 + wr + l4 * 4;
  const int n0 = bn * 128 + wc + l15;
#pragma unroll
  for (int i = 0; i < 4; ++i)
#pragma unroll
    for (int j = 0; j < 4; ++j) {
      float* dst = fco + (size_t)(m0 + i * 16) * 512 + n0 + j * 16;
#pragma unroll
      for (int r = 0; r < 4; ++r) dst[(size_t)r * 512] = acc[i][j][r];
    }
}

// ---------------- fused attention ----------------
// grid 2048: bid = qb*256 + (b*8+h)  -> all 8 qb of one (b,h) on same XCD.
// block 512 thr (8 waves), 64 q rows. No K/V LDS staging: B-frags direct
// from global (L2-resident). LDS: P bf16 [64][512] + reduction pads = 70KB.
// Barriers: 3.
__global__ __launch_bounds__(512, 4) void attn_fused(const uint16_t* __restrict__ qh,
                                                     const uint16_t* __restrict__ kh,
                                                     const uint16_t* __restrict__ vtp,
                                                     const unsigned long long* __restrict__ pm,
                                                     float* __restrict__ attn_out,
                                                     uint16_t* __restrict__ oh) {
  __shared__ uint16_t Ps[64 * 512];   // 64KB rows=q stride 1024B, XOR ((r&7)<<4)
  __shared__ float red8[64 * 9];      // padded stride 9 (bank-spread)
  __shared__ float red8b[64 * 9];

  const int bid = blockIdx.x;
  const int bh = bid & 255, qb = bid >> 8;
  const int b = bh >> 3, h = bh & 7;
  const int t = threadIdx.x, lane = t & 63, w = t >> 6;
  const int l15 = lane & 15, l4 = lane >> 4;
  const int q0 = qb * 64;
  const char* qbase = (const char*)qh + ((size_t)bh * 512 + q0) * 128;
  const char* kbase = (const char*)kh + (size_t)bh * 512 * 128;
  const char* vbase = (const char*)vtp + (size_t)bh * 64 * 1024;

  // Q A-frags direct from global (same for all waves)
  bf16x8 af[4][2];
#pragma unroll
  for (int fq = 0; fq < 4; ++fq)
#pragma unroll
    for (int kk = 0; kk < 2; ++kk)
      af[fq][kk] = *(const bf16x8*)(qbase + (fq * 16 + l15) * 128 + kk * 64 + l4 * 16);

  // ---- QK^T: K B-frags direct from global; no barriers ----
  f32x4 sacc[4][4] = {};  // [q-frag][col-frag]: c = (fc>>1)*256 + w*32 + (fc&1)*16 + l15
  __builtin_amdgcn_s_setprio(1);
#pragma unroll
  for (int fc = 0; fc < 4; ++fc) {
    int brow = (fc >> 1) * 256 + w * 32 + (fc & 1) * 16 + l15;
    bf16x8 b0 = *(const bf16x8*)(kbase + (size_t)brow * 128 + l4 * 16);
    bf16x8 b1 = *(const bf16x8*)(kbase + (size_t)brow * 128 + 64 + l4 * 16);
#pragma unroll
    for (int fq = 0; fq < 4; ++fq) {
      sacc[fq][fc] = __builtin_amdgcn_mfma_f32_16x16x32_bf16(af[fq][0], b0, sacc[fq][fc], 0, 0, 0);
      sacc[fq][fc] = __builtin_amdgcn_mfma_f32_16x16x32_bf16(af[fq][1], b1, sacc[fq][fc], 0, 0, 0);
    }
  }
  __builtin_amdgcn_s_setprio(0);

  // ---- softmax pass A: scale + mask + per-wave row max ----
  const size_t pmbase = ((size_t)b * 512 + q0) * 8;
#pragma unroll
  for (int fq = 0; fq < 4; ++fq) {
#pragma unroll
    for (int i = 0; i < 4; ++i) {
      int r = fq * 16 + l4 * 4 + i;
      unsigned long long m0 = pm[pmbase + r * 8 + (w >> 1)];
      unsigned long long m1 = pm[pmbase + r * 8 + 4 + (w >> 1)];
      int bit0 = (w & 1) * 32 + l15;
      float vmax = -3.0e38f;
#pragma unroll
      for (int fc = 0; fc < 4; ++fc) {
        unsigned long long word = (fc < 2) ? m0 : m1;
        bool mk = (word >> (bit0 + (fc & 1) * 16)) & 1ull;
        float sv = sacc[fq][fc][i] * 0.125f;
        sv = mk ? -1.0e30f : sv;
        sacc[fq][fc][i] = sv;
        vmax = fmaxf(vmax, sv);
      }
      vmax = fmaxf(vmax, __shfl_xor(vmax, 1));
      vmax = fmaxf(vmax, __shfl_xor(vmax, 2));
      vmax = fmaxf(vmax, __shfl_xor(vmax, 4));
      vmax = fmaxf(vmax, __shfl_xor(vmax, 8));
      if (l15 == 0) red8[r * 9 + w] = vmax;
    }
  }
  __syncthreads();  // #1

  // ---- pass B: full-row max (each thread reduces 8 partials), exp, sums ----
#pragma unroll
  for (int fq = 0; fq < 4; ++fq) {
#pragma unroll
    for (int i = 0; i < 4; ++i) {
      int r = fq * 16 + l4 * 4 + i;
      float mx = red8[r * 9];
#pragma unroll
      for (int j = 1; j < 8; ++j) mx = fmaxf(mx, red8[r * 9 + j]);
      float s = 0.f;
#pragma unroll
      for (int fc = 0; fc < 4; ++fc) {
        float p = __expf(sacc[fq][fc][i] - mx);  // all-masked row -> uniform, matches ref
        sacc[fq][fc][i] = p;
        s += p;
      }
      s += __shfl_xor(s, 1); s += __shfl_xor(s, 2);
      s += __shfl_xor(s, 4); s += __shfl_xor(s, 8);
      if (l15 == 0) red8b[r * 9 + w] = s;
    }
  }
  __syncthreads();  // #2

  // ---- pass C: normalize, write P (bf16) to LDS ----
#pragma unroll
  for (int fq = 0; fq < 4; ++fq) {
#pragma unroll
    for (int i = 0; i < 4; ++i) {
      int r = fq * 16 + l4 * 4 + i;
      float s = red8b[r * 9];
#pragma unroll
      for (int j = 1; j < 8; ++j) s += red8b[r * 9 + j];
      float rinv = 1.0f / s;
#pragma unroll
      for (int fc = 0; fc < 4; ++fc) {
        int c = (fc >> 1) * 256 + w * 32 + (fc & 1) * 16 + l15;
        *(uint16_t*)((char*)Ps + r * 1024 + ((c * 2) ^ ((r & 7) << 4))) =
            f2bf(sacc[fq][fc][i] * rinv);
      }
    }
  }
  __syncthreads();  // #3

  // ---- attn_out: full-line coalesced write from Ps (issued before PV) ----
  {
    float* abase = attn_out + ((size_t)(h * 32 + b) * 512 + q0) * 512;
    int r = t >> 3, s8 = t & 7;
#pragma unroll
    for (int j = 0; j < 8; ++j) {
      bf16x8 pv = *(const bf16x8*)((const char*)Ps + r * 1024 +
                                   ((j * 128 + s8 * 16) ^ ((r & 7) << 4)));
      ushort8 u = __builtin_bit_cast(ushort8, pv);
      f32x4 lo, hi;
#pragma unroll
      for (int c = 0; c < 4; ++c) {
        lo[c] = __builtin_bit_cast(float, (uint32_t)u[c] << 16);
        hi[c] = __builtin_bit_cast(float, (uint32_t)u[c + 4] << 16);
      }
      char* dst = (char*)abase + (size_t)r * 2048 + j * 256 + s8 * 32;
      *(f32x4*)dst = lo;
      *(f32x4*)(dst + 16) = hi;
    }
  }

  // ---- PV: V B-frags direct from global; P A-frags from LDS ----
  const int dfrag = w & 3, qsel = w >> 2;
  f32x4 oacc[2] = {};
  __builtin_amdgcn_s_setprio(1);
#pragma unroll
  for (int kc = 0; kc < 16; ++kc) {
    bf16x8 bv = *(const bf16x8*)(vbase + (size_t)(dfrag * 16 + l15) * 1024 + kc * 64 + l4 * 16);
#pragma unroll
    for (int qi = 0; qi < 2; ++qi) {
      int arow = (qsel * 2 + qi) * 16 + l15;
      bf16x8 ap = *(const bf16x8*)((const char*)Ps + arow * 1024 +
                                   ((kc * 64 + l4 * 16) ^ ((arow & 7) << 4)));
      oacc[qi] = __builtin_amdgcn_mfma_f32_16x16x32_bf16(ap, bv, oacc[qi], 0, 0, 0);
    }
  }
  __builtin_amdgcn_s_setprio(0);

#pragma unroll
  for (int qi = 0; qi < 2; ++qi) {
    int qrow = (qsel * 2 + qi) * 16 + l4 * 4;
    int d = dfrag * 16 + l15;
    uint16_t* dst = oh + ((size_t)(b * 512 + q0 + qrow)) * 512 + h * 64 + d;
#pragma unroll
    for (int r = 0; r < 4; ++r) dst[(size_t)r * 512] = f2bf(oacc[qi][r]);
  }
}

// ---------------- LayerNorm (+FC bias) ----------------
__global__ __launch_bounds__(256) void ln_kernel(const float* __restrict__ x,
                                                 const float* __restrict__ bias,
                                                 const float* __restrict__ g,
                                                 const float* __restrict__ bt,
                                                 float* __restrict__ out) {
  int w = threadIdx.x >> 6, lane = threadIdx.x & 63;
  int row = blockIdx.x * 4 + w;
  const float* xr = x + (size_t)row * 512;
  float v[8];
  float s = 0.f;
#pragma unroll
  for (int j = 0; j < 8; ++j) {
    v[j] = xr[lane + j * 64] + bias[lane + j * 64];
    s += v[j];
  }
#pragma unroll
  for (int m = 32; m >= 1; m >>= 1) s += __shfl_xor(s, m);
  float mu = s * (1.f / 512.f);
  float var = 0.f;
#pragma unroll
  for (int j = 0; j < 8; ++j) { float d = v[j] - mu; var += d * d; }
#pragma unroll
  for (int m = 32; m >= 1; m >>= 1) var += __shfl_xor(var, m);
  float rstd = rsqrtf(var * (1.f / 512.f) + 1e-5f);
  float* orow = out + (size_t)row * 512;
#pragma unroll
  for (int j = 0; j < 8; ++j)
    orow[lane + j * 64] = (v[j] - mu) * rstd * g[lane + j * 64] + bt[lane + j * 64];
}

// ---------------------------------------------------------------------------
extern "C" void kernel_launch(void* const* d_in, const int* in_sizes, int n_in,
                              void* d_out, int out_size, void* d_ws, size_t ws_size,
                              hipStream_t stream) {
  (void)in_sizes; (void)n_in; (void)out_size; (void)ws_size;
  const float* q   = (const float*)d_in[0];
  const float* k   = (const float*)d_in[1];
  const float* v   = (const float*)d_in[2];
  const int*   msk = (const int*)d_in[3];
  const float* Wq  = (const float*)d_in[4];
  const float* Wk  = (const float*)d_in[5];
  const float* Wv  = (const float*)d_in[6];
  const float* fcw = (const float*)d_in[7];
  const float* fcb = (const float*)d_in[8];
  const float* lng = (const float*)d_in[9];
  const float* lnb = (const float*)d_in[10];
  float* outp = (float*)d_out;

  char* ws = (char*)d_ws;
  uint16_t* qb_  = (uint16_t*)(ws);
  uint16_t* kb_  = (uint16_t*)(ws + 16777216);
  uint16_t* vb_  = (uint16_t*)(ws + 2 * 16777216);
  uint16_t* wqb  = (uint16_t*)(ws + 3 * 16777216);
  uint16_t* wkb  = (uint16_t*)(ws + 3 * 16777216 + 524288);
  uint16_t* wvb  = (uint16_t*)(ws + 3 * 16777216 + 2 * 524288);
  uint16_t* fcwb = (uint16_t*)(ws + 3 * 16777216 + 3 * 524288);
  uint16_t* qh   = (uint16_t*)(ws + 3 * 16777216 + 4 * 524288);
  uint16_t* kh   = qh + 8388608;
  uint16_t* vt   = kh + 8388608;
  uint16_t* oh   = vt + 8388608;
  float*    fco  = (float*)(oh + 8388608);
  unsigned long long* pmask = (unsigned long long*)((char*)fco + 33554432);

  cvt_qkv<<<24576, 256, 0, stream>>>(q, k, v, qb_, kb_, vb_);
  cvt_w<<<1024, 256, 0, stream>>>(Wq, Wk, Wv, fcw, wqb, wkb, wvb, fcwb);
  pack_mask<<<32768, 256, 0, stream>>>(msk, pmask, 131072);

  gemm_proj<<<1536, 256, 0, stream>>>(qb_, kb_, vb_, wqb, wkb, wvb, qh, kh, vt);

  attn_fused<<<2048, 512, 0, stream>>>(qh, kh, vt, pmask, outp + 8388608, oh);

  gemm_fc<<<512, 256, 0, stream>>>(oh, fcwb, fco);
  ln_kernel<<<4096, 256, 0, stream>>>(fco, fcb, lng, lnb, outp);
}